// Round 14
// baseline (98.031 us; speedup 1.0000x reference)
//
#include <hip/hip_runtime.h>
#include <math.h>

// DigitCaps dynamic routing, B=256 R=1152 C=10 OUT=16 IN=8, fp32 in/out.
// Identity: b_ij(t) = dot(u_hat, Vsum), Vsum = sum of previous v -> never
// store b_ij/u_hat; recompute u_hat from W16 each iteration.
//
// 7-launch structure: conv_w + 3 x (caps_iter + caps_reduce).
// THIS ROUND: occupancy x2.5 at constant work -- chunks 128->320 (RPC=4,
// NPAIR=2), grid 1280 blocks x 4 waves = 5120 waves (4-5/SIMD resident vs 2).
// Total DS insts and VALU insts unchanged (T=2 kept). caps_iter reads x
// directly from f32 input (rows contiguous per batch, cvt_pkrtz in-kernel);
// padded rows r>=1152: clamped x address + zero W16 rows -> u=0 exactly.
// Wave-private 2-buffer LDS W staging (global_load_lds, counted vmcnt),
// DPP og-lane softmax reduction (no DS ops), barrier-free main loop,
// in-block reduce over the 4 waves.
//
// ws: s_part[80][256][160] (13.1MB) + Vsum (0.16MB) + W16[1280][1280] f16
//     (3.28MB) = 16.6MB

typedef _Float16 h2 __attribute__((ext_vector_type(2)));
typedef _Float16 h4 __attribute__((ext_vector_type(4)));

#if __has_builtin(__builtin_amdgcn_fdot2)
#define FDOT2(a, b, c) __builtin_amdgcn_fdot2((a), (b), (c), false)
#else
static __device__ __forceinline__ float FDOT2(h2 a, h2 b, float c) {
    return c + (float)a.x * (float)b.x + (float)a.y * (float)b.y;
}
#endif

static __device__ __forceinline__ h2 CVTPK(float a, float b) {
#if __has_builtin(__builtin_amdgcn_cvt_pkrtz)
    return __builtin_bit_cast(h2, __builtin_amdgcn_cvt_pkrtz(a, b));
#else
    h2 r; r.x = (_Float16)a; r.y = (_Float16)b; return r;
#endif
}

#if __has_builtin(__builtin_amdgcn_rcpf)
#define FRCP(x) __builtin_amdgcn_rcpf(x)
#else
#define FRCP(x) (1.0f / (x))
#endif

#define BCH2(u) __builtin_bit_cast(h2, (u))

// cross-lane add via DPP (VALU, not DS). 0xB1 = quad_perm xor1, 0x4E = xor2,
// 0x141 = ROW_HALF_MIRROR (completes the 8-lane sum). Verified R9/R10/R12/R13.
template<int CTRL>
static __device__ __forceinline__ float dpp_xadd(float x) {
    const int t = __builtin_amdgcn_update_dpp(
        0, __builtin_bit_cast(int, x), CTRL, 0xF, 0xF, true);
    return x + __builtin_bit_cast(float, t);
}
static __device__ __forceinline__ float og_allsum(float l) {
    l = dpp_xadd<0xB1>(l);
    l = dpp_xadd<0x4E>(l);
    l = dpp_xadd<0x141>(l);
    return l;
}

namespace {
constexpr int Bdim = 256;
constexpr int Rdim = 1152;
constexpr int Cdim = 10;
constexpr int Odim = 16;
constexpr int Idim = 8;
constexpr int CO   = 160;

constexpr int Rpad  = 1280;  // zero-padded R (pad rows: u=0 -> exact no-op)
constexpr int RPC   = 4;     // rows per chunk
constexpr int NPAIR = 2;     // row-pairs per chunk
constexpr int NQ    = 80;    // chunk-quads (= blockIdx.x range = s_part slices)
constexpr int NSP   = 80;    // s_part slices
constexpr int WROW  = Cdim * Odim * Idim;   // 1280 f16 per W row
}

// f32 -> f16 W with zero padding to Rpad rows. Coalesced both sides.
__global__ __launch_bounds__(256)
void conv_w(const float* __restrict__ W, _Float16* __restrict__ W16)
{
    const int i = blockIdx.x * 256 + threadIdx.x;    // < 409600
    const int r = i / (WROW / 4);
    h4 o = { (_Float16)0.f, (_Float16)0.f, (_Float16)0.f, (_Float16)0.f };
    if (r < Rdim) {
        const float4 v = reinterpret_cast<const float4*>(W)[i];
        o = { (_Float16)v.x, (_Float16)v.y, (_Float16)v.z, (_Float16)v.w };
    }
    reinterpret_cast<h4*>(W16)[i] = o;
}

// Stage one W row-pair (2560 f16 = 5 KB) linearly into a wave-private buffer.
__device__ __forceinline__ void stagepair(const _Float16* __restrict__ src,
                                          _Float16* dst, int lane)
{
#pragma unroll
    for (int k = 0; k < 5; ++k) {
        const _Float16* s = src + (size_t)(k * 64 + lane) * 8;   // 16B granule
        _Float16* d = dst + k * 512;                             // wave-uniform
        __builtin_amdgcn_global_load_lds((const __attribute__((address_space(1))) void*)s,
                                         (__attribute__((address_space(3))) void*)d,
                                         16, 0, 0);
    }
}

template<bool FIRST>
__global__ __launch_bounds__(256)
void caps_iter(const float* __restrict__ xf, const _Float16* __restrict__ W16,
               const float* __restrict__ Vsum, float* __restrict__ s_part)
{
    __shared__ __align__(16) _Float16 Wst[4][2][2560];   // 40960 B exactly

    const int tid  = threadIdx.x;
    const int wv   = tid >> 6;
    const int lane = tid & 63;
    const int og   = lane & 7;          // o-group: o = og*2, og*2+1
    const int bl   = lane >> 3;         // 0..7

    const int quad = blockIdx.x;        // 0..79
    const int bgrp = blockIdx.y;        // 0..15
    const int chunk = quad * 4 + wv;    // 0..319
    const int r0    = chunk * RPC;
    const int b0    = bgrp * 16 + bl;
    const int b1    = b0 + 8;

    float va0[Cdim], vb0[Cdim], va1[Cdim], vb1[Cdim];
    if constexpr (!FIRST) {
#pragma unroll
        for (int c = 0; c < Cdim; ++c) {
            const float2 p = *reinterpret_cast<const float2*>(
                Vsum + (size_t)b0 * CO + c * Odim + og * 2);
            va0[c] = p.x; vb0[c] = p.y;
            const float2 q = *reinterpret_cast<const float2*>(
                Vsum + (size_t)b1 * CO + c * Odim + og * 2);
            va1[c] = q.x; vb1[c] = q.y;
        }
    }

    float sA0[Cdim], sA1[Cdim], sB0[Cdim], sB1[Cdim];
#pragma unroll
    for (int c = 0; c < Cdim; ++c) { sA0[c]=0.f; sA1[c]=0.f; sB0[c]=0.f; sB1[c]=0.f; }

    const _Float16* Wr = W16 + (size_t)r0 * WROW;
    const float* xb0 = xf + (size_t)b0 * (Rdim * Idim);
    const float* xb1 = xf + (size_t)b1 * (Rdim * Idim);

    // x row-pair base (clamped for padded rows; W16 zeros make u=0 there)
    auto xoff = [&](int p) -> int {
        int r = r0 + p * 2;
        return (r > Rdim - 2 ? Rdim - 2 : r) * Idim;
    };

    // prologue: stage(0) [5] + x(0) [8 float4 loads] -> 13 outstanding
    stagepair(Wr, &Wst[wv][0][0], lane);
    float4 xc[8];
    {
        const int o0 = xoff(0);
        xc[0] = *reinterpret_cast<const float4*>(xb0 + o0);
        xc[1] = *reinterpret_cast<const float4*>(xb0 + o0 + 4);
        xc[2] = *reinterpret_cast<const float4*>(xb0 + o0 + 8);
        xc[3] = *reinterpret_cast<const float4*>(xb0 + o0 + 12);
        xc[4] = *reinterpret_cast<const float4*>(xb1 + o0);
        xc[5] = *reinterpret_cast<const float4*>(xb1 + o0 + 4);
        xc[6] = *reinterpret_cast<const float4*>(xb1 + o0 + 8);
        xc[7] = *reinterpret_cast<const float4*>(xb1 + o0 + 12);
    }

    for (int p = 0; p < NPAIR; ++p) {
        // drain stage(p) [oldest 5]; keep x(p) [8] in flight
        asm volatile("s_waitcnt vmcnt(8)" ::: "memory");

        const _Float16* stcur = &Wst[wv][p & 1][0];

        float4 xn[8];
        if (p + 1 < NPAIR) {
            stagepair(Wr + (size_t)(p + 1) * 2 * WROW, &Wst[wv][(p + 1) & 1][0], lane);
            const int o1 = xoff(p + 1);
            xn[0] = *reinterpret_cast<const float4*>(xb0 + o1);
            xn[1] = *reinterpret_cast<const float4*>(xb0 + o1 + 4);
            xn[2] = *reinterpret_cast<const float4*>(xb0 + o1 + 8);
            xn[3] = *reinterpret_cast<const float4*>(xb0 + o1 + 12);
            xn[4] = *reinterpret_cast<const float4*>(xb1 + o1);
            xn[5] = *reinterpret_cast<const float4*>(xb1 + o1 + 4);
            xn[6] = *reinterpret_cast<const float4*>(xb1 + o1 + 8);
            xn[7] = *reinterpret_cast<const float4*>(xb1 + o1 + 12);
        }

#pragma unroll
        for (int rl = 0; rl < 2; ++rl) {
            // pack this row's x to f16 (batch A = b0, batch B = b1)
            const float4 pa0 = xc[rl * 2 + 0], pa1 = xc[rl * 2 + 1];
            const float4 pb0 = xc[rl * 2 + 4], pb1 = xc[rl * 2 + 5];
            const h2 a0 = CVTPK(pa0.x, pa0.y), a1 = CVTPK(pa0.z, pa0.w);
            const h2 a2 = CVTPK(pa1.x, pa1.y), a3 = CVTPK(pa1.z, pa1.w);
            const h2 e0 = CVTPK(pb0.x, pb0.y), e1 = CVTPK(pb0.z, pb0.w);
            const h2 e2 = CVTPK(pb1.x, pb1.y), e3 = CVTPK(pb1.z, pb1.w);

            const _Float16* wbase = stcur + rl * WROW + og * 16;
            float uA0[Cdim], uA1[Cdim], uB0[Cdim], uB1[Cdim];
#pragma unroll
            for (int c = 0; c < Cdim; ++c) {
                const uint4* wp = reinterpret_cast<const uint4*>(wbase + c * (Odim * Idim));
                const uint4 w0 = wp[0], w1 = wp[1];
                float t;
                t = FDOT2(BCH2(w0.x), a0, 0.f);  t = FDOT2(BCH2(w0.y), a1, t);
                t = FDOT2(BCH2(w0.z), a2, t);    uA0[c] = FDOT2(BCH2(w0.w), a3, t);
                t = FDOT2(BCH2(w1.x), a0, 0.f);  t = FDOT2(BCH2(w1.y), a1, t);
                t = FDOT2(BCH2(w1.z), a2, t);    uA1[c] = FDOT2(BCH2(w1.w), a3, t);
                t = FDOT2(BCH2(w0.x), e0, 0.f);  t = FDOT2(BCH2(w0.y), e1, t);
                t = FDOT2(BCH2(w0.z), e2, t);    uB0[c] = FDOT2(BCH2(w0.w), e3, t);
                t = FDOT2(BCH2(w1.x), e0, 0.f);  t = FDOT2(BCH2(w1.y), e1, t);
                t = FDOT2(BCH2(w1.z), e2, t);    uB1[c] = FDOT2(BCH2(w1.w), e3, t);
            }

            if constexpr (FIRST) {
#pragma unroll
                for (int c = 0; c < Cdim; ++c) {
                    sA0[c] += 0.1f * uA0[c];  sA1[c] += 0.1f * uA1[c];
                    sB0[c] += 0.1f * uB0[c];  sB1[c] += 0.1f * uB1[c];
                }
            } else {
                float eA[Cdim], eB[Cdim];
                float sumA = 0.f, sumB = 0.f;
#pragma unroll
                for (int c = 0; c < Cdim; ++c) {
                    float lA = uA0[c] * va0[c] + uA1[c] * vb0[c];
                    lA = og_allsum(lA);
                    eA[c] = __expf(lA);  sumA += eA[c];
                    float lB = uB0[c] * va1[c] + uB1[c] * vb1[c];
                    lB = og_allsum(lB);
                    eB[c] = __expf(lB);  sumB += eB[c];
                }
                const float rA = FRCP(sumA), rB = FRCP(sumB);
#pragma unroll
                for (int c = 0; c < Cdim; ++c) {
                    const float cwA = eA[c] * rA;
                    sA0[c] += cwA * uA0[c];  sA1[c] += cwA * uA1[c];
                    const float cwB = eB[c] * rB;
                    sB0[c] += cwB * uB0[c];  sB1[c] += cwB * uB1[c];
                }
            }
        }

        if (p + 1 < NPAIR) {
#pragma unroll
            for (int q = 0; q < 8; ++q) xc[q] = xn[q];
        }
    }

    // ---- in-block reduce over 4 waves (reuse Wst as f32 [4][16][160])
    __syncthreads();
    float* red = reinterpret_cast<float*>(&Wst[0][0][0]);
    {
        float* p0 = red + (wv * 16 + bl) * CO + og * 2;
        float* p1 = red + (wv * 16 + bl + 8) * CO + og * 2;
#pragma unroll
        for (int c = 0; c < Cdim; ++c) {
            *reinterpret_cast<float2*>(p0 + c * Odim) = make_float2(sA0[c], sA1[c]);
            *reinterpret_cast<float2*>(p1 + c * Odim) = make_float2(sB0[c], sB1[c]);
        }
    }
    __syncthreads();
#pragma unroll
    for (int k = 0; k < 10; ++k) {
        const int j = k * 256 + tid;          // 0..2559 = 16 b x 160 co
        const float t = red[j] + red[j + 2560] + red[j + 5120] + red[j + 7680];
        const int b2 = j / CO;
        const int co = j - b2 * CO;
        s_part[((size_t)quad * Bdim + bgrp * 16 + b2) * CO + co] = t;
    }
}

// Sum the NSP partials, squash; MODE 0: Vsum = v (replaces memset),
// MODE 1: Vsum += v, MODE 2: out = v.
template<int MODE>
__global__ __launch_bounds__(256)
void caps_reduce(const float* __restrict__ s_part, float* __restrict__ Vsum,
                 float* __restrict__ out)
{
    const int idx = blockIdx.x * 256 + threadIdx.x;   // < 40960 = B*C*O
    float s = 0.f;
#pragma unroll 8
    for (int k = 0; k < NSP; ++k) s += s_part[(size_t)k * (Bdim * CO) + idx];

    float ssq = s * s;
    ssq += __shfl_xor(ssq, 1);
    ssq += __shfl_xor(ssq, 2);
    ssq += __shfl_xor(ssq, 4);
    ssq += __shfl_xor(ssq, 8);

    const float mag = sqrtf(ssq + 1e-8f);
    const float v = ssq / (1.f + ssq) * s / (mag + 1e-8f);

    if constexpr (MODE == 2) out[idx] = v;
    else if constexpr (MODE == 1) Vsum[idx] += v;
    else Vsum[idx] = v;
}

extern "C" void kernel_launch(void* const* d_in, const int* in_sizes, int n_in,
                              void* d_out, int out_size, void* d_ws, size_t ws_size,
                              hipStream_t stream)
{
    const float* x = (const float*)d_in[0];   // [256,1152,8]
    const float* W = (const float*)d_in[1];   // [1152,10,16,8]
    float* out = (float*)d_out;               // [256,10,16]

    float* s_part = (float*)d_ws;                           // 80*256*160 f32
    float* Vsum   = s_part + (size_t)NSP * Bdim * CO;       // 256*160 f32
    _Float16* W16 = (_Float16*)(Vsum + Bdim * CO);          // 1280*1280 f16

    conv_w<<<dim3(1600), dim3(256), 0, stream>>>(W, W16);   // 409600/256

    const dim3 gi(NQ, Bdim / 16);    // (80, 16) = 1280 blocks, 4 waves each
    const dim3 bi(256);
    const dim3 gr((Bdim * CO) / 256);
    const dim3 br(256);

    // it 0
    caps_iter<true><<<gi, bi, 0, stream>>>(x, W16, Vsum, s_part);
    caps_reduce<0><<<gr, br, 0, stream>>>(s_part, Vsum, out);
    // it 1
    caps_iter<false><<<gi, bi, 0, stream>>>(x, W16, Vsum, s_part);
    caps_reduce<1><<<gr, br, 0, stream>>>(s_part, Vsum, out);
    // it 2 (final -> d_out)
    caps_iter<false><<<gi, bi, 0, stream>>>(x, W16, Vsum, s_part);
    caps_reduce<2><<<gr, br, 0, stream>>>(s_part, Vsum, out);
}